// Round 9
// baseline (434.510 us; speedup 1.0000x reference)
//
#include <hip/hip_runtime.h>
#include <hip/hip_bf16.h>

typedef __attribute__((ext_vector_type(8))) short short8;
typedef __attribute__((ext_vector_type(4))) float f32x4;
typedef __attribute__((ext_vector_type(16))) float f32x16;

#define DEV __device__ __forceinline__

DEV float bf2f(ushort u){ union { float f; unsigned int i; } x; x.i = ((unsigned int)u)<<16; return x.f; }
DEV ushort f2bf(float f){ union { float fl; unsigned int i; } x; x.fl = f; unsigned int r = x.i + 0x7fffu + ((x.i>>16)&1u); return (ushort)(r>>16); }

DEV void gl2lds16(const ushort* g, ushort* l){
  __builtin_amdgcn_global_load_lds((const __attribute__((address_space(1))) void*)g,
                                   (__attribute__((address_space(3))) void*)l, 16, 0, 0);
}
DEV f32x16 mfma32(short8 a, short8 b, f32x16 c){
  return __builtin_amdgcn_mfma_f32_32x32x16_bf16(a, b, c, 0, 0, 0);
}
DEV uint cvtpk(float lo, float hi){
  uint r; asm("v_cvt_pk_bf16_f32 %0, %1, %2" : "=v"(r) : "v"(lo), "v"(hi));
  return r;
}
DEV uint q8(float v){
  float c = fminf(fmaxf(v, -127.f), 127.f);
  return ((uint)(int)rintf(c)) & 255u;
}

// ---------------- fp32 -> bf16 convert (Er only) ----------------
__global__ void cvt_f2b(const float* __restrict__ in, ushort* __restrict__ out, int n){
  int i = blockIdx.x*blockDim.x + threadIdx.x;
  int stride = gridDim.x*blockDim.x;
  for (; i < n; i += stride) out[i] = f2bf(in[i]);
}

// ---------------- fp32 [K][N] -> bf16 [N][K+pad] tiled transpose ----------------
__global__ __launch_bounds__(256) void wt_cvt(const float* __restrict__ in, ushort* __restrict__ out,
                                              int K, int N, int ldk){
  const int n0 = blockIdx.x*64, k0 = blockIdx.y*64;
  __shared__ float T[64][65];
  const int tid = threadIdx.x;
  const int r = tid>>4, c = (tid&15)*4;
  #pragma unroll
  for (int p=0;p<4;p++){
    float4 v = *(const float4*)&in[(size_t)(k0 + p*16 + r)*N + n0 + c];
    T[p*16+r][c+0]=v.x; T[p*16+r][c+1]=v.y; T[p*16+r][c+2]=v.z; T[p*16+r][c+3]=v.w;
  }
  __syncthreads();
  #pragma unroll
  for (int p=0;p<4;p++){
    int n = p*16 + r;
    ushort u0 = f2bf(T[c+0][n]), u1 = f2bf(T[c+1][n]), u2 = f2bf(T[c+2][n]), u3 = f2bf(T[c+3][n]);
    ushort4 u = make_ushort4(u0,u1,u2,u3);
    *(ushort4*)&out[(size_t)(n0+n)*ldk + k0 + c] = u;
  }
}

// ---------------- V transpose: qkv V-part [n][hd] -> Vt [(bh*64+hd)][n] ----------------
__global__ __launch_bounds__(256) void vt_k(const ushort* __restrict__ qkv, ushort* __restrict__ vt){
  const int bh = blockIdx.y; const int b = bh>>4, h = bh&15;
  const int n0 = blockIdx.x*64;
  __shared__ ushort T[64][66];
  const int tid = threadIdx.x;
  const int r = tid>>3, c8 = (tid&7)*8;
  #pragma unroll
  for (int p=0;p<2;p++){
    int row = p*32 + r;
    short8 v = *(const short8*)&qkv[(size_t)(b*1024 + n0 + row)*3200 + 2048 + h*64 + c8];
    #pragma unroll
    for (int i=0;i<8;i++) T[row][c8+i] = ((ushort*)&v)[i];
  }
  __syncthreads();
  #pragma unroll
  for (int p=0;p<2;p++){
    int d = p*32 + r;
    union { ushort u[8]; short8 v; } o;
    #pragma unroll
    for (int i=0;i<8;i++) o.u[i] = T[c8+i][d];
    *(short8*)&vt[(size_t)(bh*64 + d)*1152 + n0 + c8] = o.v;
  }
}

// ---------------- LayerNorm over C=1024 ----------------
__global__ __launch_bounds__(256) void ln_rows(const float* __restrict__ in,
                                               const float* __restrict__ g,
                                               const float* __restrict__ bta,
                                               ushort* __restrict__ out, int ldo){
  int row = blockIdx.x; int tid = threadIdx.x;
  const float* x = in + (size_t)row*1024;
  float v[4]; float s = 0.f;
  #pragma unroll
  for (int i=0;i<4;i++){ v[i] = x[tid + 256*i]; s += v[i]; }
  __shared__ float rbuf[256];
  rbuf[tid] = s; __syncthreads();
  for (int off=128; off>0; off>>=1){ if (tid<off) rbuf[tid]+=rbuf[tid+off]; __syncthreads(); }
  float mean = rbuf[0] * (1.f/1024.f);
  __syncthreads();
  float s2 = 0.f;
  #pragma unroll
  for (int i=0;i<4;i++){ float d=v[i]-mean; s2 += d*d; }
  rbuf[tid] = s2; __syncthreads();
  for (int off=128; off>0; off>>=1){ if (tid<off) rbuf[tid]+=rbuf[tid+off]; __syncthreads(); }
  float var = rbuf[0] * (1.f/1024.f);
  float rstd = rsqrtf(var + 1e-5f);
  #pragma unroll
  for (int i=0;i<4;i++){ int c = tid+256*i; out[(size_t)row*ldo+c] = f2bf((v[i]-mean)*rstd*g[c]+bta[c]); }
}

// ---------------- time-embedding GEMM ----------------
__global__ __launch_bounds__(256) void tq_gemm2(const float* __restrict__ t, const float* __restrict__ tw,
                                                const float* __restrict__ tb, float* __restrict__ tq){
  const int tid = threadIdx.x;
  const int j = blockIdx.x*64 + (tid & 63);
  const int sl = tid >> 6;
  float acc[4] = {0.f,0.f,0.f,0.f};
  for (int k = sl*64; k < sl*64+64; ++k){
    float wv = tw[(size_t)k*3072 + j];
    #pragma unroll
    for (int b=0;b<4;b++) acc[b] = fmaf(t[b*256+k], wv, acc[b]);
  }
  __shared__ float red[4][4][64];
  #pragma unroll
  for (int b=0;b<4;b++) red[sl][b][tid&63] = acc[b];
  __syncthreads();
  if (sl == 0){
    #pragma unroll
    for (int b=0;b<4;b++)
      tq[b*3072 + j] = red[0][b][tid&63] + red[1][b][tid&63] + red[2][b][tid&63] + red[3][b][tid&63] + tb[j];
  }
}

// ---------------- gemm4: 128xTN tile, BK=32, double-buffered LDS 2-phase pipeline ----------------
template<int EPI, int TN>
__global__ __launch_bounds__(256) void gemm4(
    const ushort* __restrict__ A, const ushort* __restrict__ Bt,
    const float* __restrict__ bias, const float* __restrict__ extra,
    ushort* __restrict__ outb, float* __restrict__ outf,
    int K, int lda, int ldb, int ldo, int lde, int nbx)
{
  constexpr int NJ = TN/32;
  __shared__ __align__(16) ushort Al[2][128*32];
  __shared__ __align__(16) ushort Bl[2][TN*32];
  const int nwg = gridDim.x, cpx = nwg >> 3;
  const int bid = blockIdx.x;
  const int swz = (bid & 7)*cpx + (bid >> 3);
  const int m0 = (swz / nbx)*128, n0 = (swz % nbx)*TN;
  const int tid = threadIdx.x, lane = tid & 63, wid = tid >> 6;
  const int wm = (wid&1)*64, wn = (wid>>1)*(TN/2);
  const int l15 = lane&15, l4 = lane>>4;
  f32x4 acc[4][NJ];
  #pragma unroll
  for (int i=0;i<4;i++)
    #pragma unroll
    for (int jx=0;jx<NJ;jx++){ acc[i][jx][0]=0.f; acc[i][jx][1]=0.f; acc[i][jx][2]=0.f; acc[i][jx][3]=0.f; }
  const ushort* a0p = A + (size_t)(m0 + (tid>>2))*lda + (tid&3)*8;
  const ushort* a1p = A + (size_t)(m0 + 64 + (tid>>2))*lda + (tid&3)*8;
  const ushort* b0p = Bt + (size_t)(n0 + (tid>>2))*ldb + (tid&3)*8;
  const ushort* b1p = nullptr;
  if constexpr (TN==128) b1p = Bt + (size_t)(n0 + 64 + (tid>>2))*ldb + (tid&3)*8;
  const int lsl = tid*8, lsh = (tid+256)*8;

  gl2lds16(a0p, &Al[0][lsl]);
  gl2lds16(a1p, &Al[0][lsh]);
  gl2lds16(b0p, &Bl[0][lsl]);
  if constexpr (TN==128) gl2lds16(b1p, &Bl[0][lsh]);
  __syncthreads();

  const int nk = K >> 5;
  for (int it=0; it<nk; ++it){
    const int cur = it & 1;
    ushort* Ac = Al[cur];  ushort* Bc = Bl[cur];
    if (it+1 < nk){
      const int k1 = (it+1) << 5;
      gl2lds16(a0p + k1, &Al[cur^1][lsl]);
      gl2lds16(a1p + k1, &Al[cur^1][lsh]);
      gl2lds16(b0p + k1, &Bl[cur^1][lsl]);
      if constexpr (TN==128) gl2lds16(b1p + k1, &Bl[cur^1][lsh]);
    }
    short8 af[4], bfr[NJ];
    #pragma unroll
    for (int mi=0;mi<4;mi++) af[mi]  = *(const short8*)&Ac[(wm + mi*16 + l15)*32 + l4*8];
    #pragma unroll
    for (int nj=0;nj<NJ;nj++) bfr[nj] = *(const short8*)&Bc[(wn + nj*16 + l15)*32 + l4*8];
    #pragma unroll
    for (int mi=0;mi<4;mi++)
      #pragma unroll
      for (int nj=0;nj<NJ;nj++)
        acc[mi][nj] = __builtin_amdgcn_mfma_f32_16x16x32_bf16(af[mi], bfr[nj], acc[mi][nj], 0,0,0);
    __syncthreads();
  }
  #pragma unroll
  for (int mi=0;mi<4;mi++)
    #pragma unroll
    for (int nj=0;nj<NJ;nj++)
      #pragma unroll
      for (int j=0;j<4;j++){
        int row = m0 + wm + mi*16 + l4*4 + j;
        int col = n0 + wn + nj*16 + l15;
        float v = acc[mi][nj][j] + bias[col];
        if constexpr (EPI==0){ v += extra[(size_t)(row>>10)*lde + col]; outb[(size_t)row*ldo+col] = f2bf(v); }
        else if constexpr (EPI==1){ v += extra[(size_t)row*lde + col]; outf[(size_t)row*ldo+col] = v; }
        else { v = 0.5f*v*(1.f+erff(v*0.70710678118f)); outb[(size_t)row*ldo+col] = f2bf(v); }
      }
}

// ---------------- attn8: int8-bias LDS rel-skew + fixed-base (M=0) 32x32 flash ----------------
// grid 2048 = 64 bh x 32 row-tiles of 32 q-rows; 4 waves split kv 4-way, plain-sum merge.
// RRF8 layout: row lr stride 1036 BYTES; entry e = round(RR[r0+lr][e]*log2e*64) as int8.
// bias read: d = c - r; off = d<=0 ? 1023+d : 1034+d (d==1 -> zero slot; d>=2 -> row lr+1 via overlap).
// Softmax: p = exp2(S*0.18034 + b/64) with NO max tracking (logits provably < ~6; f32-safe).
__global__ __launch_bounds__(256,4) void attn8(
    const ushort* __restrict__ qkv, const ushort* __restrict__ Er,
    const ushort* __restrict__ Vt, ushort* __restrict__ out)
{
  const int bid0 = blockIdx.x;
  const int swz = (bid0 & 7)*256 + (bid0 >> 3);
  const int bh = swz >> 5, b = bh >> 4, h = bh & 15;
  const int rt = swz & 31;
  const int r0 = rt*32;
  const int tid = threadIdx.x, w = tid >> 6, lane = tid & 63;
  const int l31 = lane & 31, hi = lane >> 5;

  __shared__ __align__(16) signed char RRF8[34704];   // 33x1036 int8 bias (34188) + lsum[4][32] @34192
  ushort* Obuf = (ushort*)RRF8;                       // aliased after phase-2: [4][32][68]
  float*  ml   = (float*)(RRF8 + 34192);              // [4][32] lsum

  const ushort* Qp = qkv + (size_t)b*1024*3200 + h*64;
  const ushort* Kp = Qp + 1024;
  const ushort* Vp = Vt + (size_t)bh*64*1152;

  const int r = r0 + l31;
  short8 qf0 = *(const short8*)(Qp + (size_t)r*3200 +      hi*8);
  short8 qf1 = *(const short8*)(Qp + (size_t)r*3200 + 16 + hi*8);
  short8 qf2 = *(const short8*)(Qp + (size_t)r*3200 + 32 + hi*8);
  short8 qf3 = *(const short8*)(Qp + (size_t)r*3200 + 48 + hi*8);

  if (tid < 32) RRF8[tid*1036 + 1035] = 0;            // diagonal-zero slots

  // Phase 1: RR rows r0..r0+31 (wave w covers e-quarter), int8 encode (x 64*log2e)
  const float ESC = 92.332481f;                       // 64 * log2(e)
  for (int t=0; t<8; ++t){
    const int e0 = w*256 + t*32;
    const ushort* ep = Er + (size_t)(e0 + l31)*64 + hi*8;
    short8 ea0 = *(const short8*)(ep);
    short8 ea1 = *(const short8*)(ep + 16);
    short8 ea2 = *(const short8*)(ep + 32);
    short8 ea3 = *(const short8*)(ep + 48);
    f32x16 acc = {};
    acc = mfma32(ea0, qf0, acc);
    acc = mfma32(ea1, qf1, acc);
    acc = mfma32(ea2, qf2, acc);
    acc = mfma32(ea3, qf3, acc);
    #pragma unroll
    for (int q=0;q<4;q++){
      int e = e0 + 8*q + 4*hi;
      uint u = q8(acc[4*q+0]*ESC) | (q8(acc[4*q+1]*ESC)<<8)
             | (q8(acc[4*q+2]*ESC)<<16) | (q8(acc[4*q+3]*ESC)<<24);
      *(uint*)(RRF8 + l31*1036 + e) = u;
    }
  }
  // extra row r0+32 (upper-diagonal source for q-row r0+31): VALU dot, 4 e per thread
  {
    const int q32r = min(r0 + 32, 1023);              // r0=992's row-32 slice is never read
    const ushort* q32 = Qp + (size_t)q32r*3200;
    const int e4 = tid*4;
    float a[4] = {0.f,0.f,0.f,0.f};
    #pragma unroll
    for (int c8=0;c8<8;c8++){
      short8 qv = *(const short8*)(q32 + c8*8);
      float qx[8];
      #pragma unroll
      for (int i=0;i<8;i++) qx[i] = bf2f(((ushort*)&qv)[i]);
      #pragma unroll
      for (int e=0;e<4;e++){
        short8 ev = *(const short8*)(Er + (size_t)(e4+e)*64 + c8*8);
        #pragma unroll
        for (int i=0;i<8;i++) a[e] = fmaf(qx[i], bf2f(((ushort*)&ev)[i]), a[e]);
      }
    }
    uint u = q8(a[0]*ESC) | (q8(a[1]*ESC)<<8) | (q8(a[2]*ESC)<<16) | (q8(a[3]*ESC)<<24);
    *(uint*)(RRF8 + 33152 + e4) = u;
  }
  __syncthreads();

  // Phase 2: flash over this wave's kv quarter (8 tiles of 32), fixed-base softmax
  const int rbase = l31*1036;
  const int kvbase = w*256;
  f32x16 O0 = {}, O1 = {};
  float lsum = 0.f;

  short8 kA0 = *(const short8*)(Kp + (size_t)(kvbase + l31)*3200 +      hi*8);
  short8 kA1 = *(const short8*)(Kp + (size_t)(kvbase + l31)*3200 + 16 + hi*8);
  short8 kA2 = *(const short8*)(Kp + (size_t)(kvbase + l31)*3200 + 32 + hi*8);
  short8 kA3 = *(const short8*)(Kp + (size_t)(kvbase + l31)*3200 + 48 + hi*8);
  short8 kB0, kB1, kB2, kB3;

  auto step = [&](short8& ka0, short8& ka1, short8& ka2, short8& ka3,
                  short8& kn0, short8& kn1, short8& kn2, short8& kn3, int t){
    const int c0 = kvbase + t*32;
    if (t < 7){
      const ushort* kp = Kp + (size_t)(c0 + 32 + l31)*3200 + hi*8;
      kn0 = *(const short8*)(kp);
      kn1 = *(const short8*)(kp + 16);
      kn2 = *(const short8*)(kp + 32);
      kn3 = *(const short8*)(kp + 48);
    }
    // bias reads (int8, hoisted; hide under QK MFMAs)
    signed char bs[16];
    #pragma unroll
    for (int q=0;q<4;q++)
      #pragma unroll
      for (int j=0;j<4;j++){
        int c = c0 + 8*q + 4*hi + j;
        int d = c - r;
        int off = (d<=0) ? (1023+d) : (1034+d);
        bs[4*q+j] = RRF8[rbase + off];
      }
    short8 v00 = *(const short8*)(Vp + (size_t)l31*1152      + c0 +      hi*8);
    short8 v01 = *(const short8*)(Vp + (size_t)l31*1152      + c0 + 16 + hi*8);
    short8 v10 = *(const short8*)(Vp + (size_t)(32+l31)*1152 + c0 +      hi*8);
    short8 v11 = *(const short8*)(Vp + (size_t)(32+l31)*1152 + c0 + 16 + hi*8);
    f32x16 S = {};
    __builtin_amdgcn_s_setprio(1);
    S = mfma32(ka0, qf0, S);
    S = mfma32(ka1, qf1, S);
    S = mfma32(ka2, qf2, S);
    S = mfma32(ka3, qf3, S);
    __builtin_amdgcn_s_setprio(0);
    float p[16];
    float s0=0.f, s1=0.f, s2=0.f, s3=0.f;
    #pragma unroll
    for (int i=0;i<16;i++){
      p[i] = __builtin_amdgcn_exp2f(fmaf(S[i], 0.18033688f, (float)bs[i]*0.015625f));
      if ((i&3)==0) s0 += p[i]; else if ((i&3)==1) s1 += p[i];
      else if ((i&3)==2) s2 += p[i]; else s3 += p[i];
    }
    lsum += (s0+s1)+(s2+s3);
    uint W00=cvtpk(p[0],p[1]),   W01=cvtpk(p[2],p[3]);
    uint W10=cvtpk(p[4],p[5]),   W11=cvtpk(p[6],p[7]);
    uint W20=cvtpk(p[8],p[9]),   W21=cvtpk(p[10],p[11]);
    uint W30=cvtpk(p[12],p[13]), W31=cvtpk(p[14],p[15]);
    uint x00 = (uint)__shfl_xor((int)(hi? W00 : W10), 32, 64);
    uint x01 = (uint)__shfl_xor((int)(hi? W01 : W11), 32, 64);
    uint x10 = (uint)__shfl_xor((int)(hi? W20 : W30), 32, 64);
    uint x11 = (uint)__shfl_xor((int)(hi? W21 : W31), 32, 64);
    union { uint u[4]; short8 v; } pf0, pf1;
    pf0.u[0] = hi ? x00 : W00;  pf0.u[1] = hi ? x01 : W01;
    pf0.u[2] = hi ? W10 : x00;  pf0.u[3] = hi ? W11 : x01;
    pf1.u[0] = hi ? x10 : W20;  pf1.u[1] = hi ? x11 : W21;
    pf1.u[2] = hi ? W30 : x10;  pf1.u[3] = hi ? W31 : x11;
    __builtin_amdgcn_s_setprio(1);
    O0 = mfma32(v00, pf0.v, O0);
    O0 = mfma32(v01, pf1.v, O0);
    O1 = mfma32(v10, pf0.v, O1);
    O1 = mfma32(v11, pf1.v, O1);
    __builtin_amdgcn_s_setprio(0);
  };
  for (int t=0;t<8;t+=2){
    step(kA0,kA1,kA2,kA3, kB0,kB1,kB2,kB3, t);
    step(kB0,kB1,kB2,kB3, kA0,kA1,kA2,kA3, t+1);
  }
  lsum = lsum + __shfl_xor(lsum, 32, 64);

  __syncthreads();   // all RRF8 bias reads done; safe to alias Obuf
  #pragma unroll
  for (int q=0;q<4;q++){
    int d = 8*q + 4*hi;
    uint2 w0, w1;
    w0.x = cvtpk(O0[4*q+0], O0[4*q+1]); w0.y = cvtpk(O0[4*q+2], O0[4*q+3]);
    w1.x = cvtpk(O1[4*q+0], O1[4*q+1]); w1.y = cvtpk(O1[4*q+2], O1[4*q+3]);
    *(uint2*)&Obuf[(w*32 + l31)*68 + d] = w0;
    *(uint2*)&Obuf[(w*32 + l31)*68 + 32 + d] = w1;
  }
  if (hi == 0) ml[w*32 + l31] = lsum;
  __syncthreads();
  // 4-way merge: plain sums (all waves share base M=0)
  {
    const int row = tid >> 3, ds8 = (tid & 7)*8;
    float den = ml[row] + ml[32+row] + ml[64+row] + ml[96+row];
    float inv = 1.f/den;
    float num[8] = {0.f,0.f,0.f,0.f,0.f,0.f,0.f,0.f};
    #pragma unroll
    for (int w2=0;w2<4;w2++){
      uint2 o0 = *(const uint2*)&Obuf[(w2*32 + row)*68 + ds8];
      uint2 o1 = *(const uint2*)&Obuf[(w2*32 + row)*68 + ds8 + 4];
      const ushort* ou0 = (const ushort*)&o0;
      const ushort* ou1 = (const ushort*)&o1;
      #pragma unroll
      for (int i=0;i<4;i++){ num[i] += bf2f(ou0[i]); num[4+i] += bf2f(ou1[i]); }
    }
    union { uint u[4]; short8 v; } ov;
    ov.u[0] = cvtpk(num[0]*inv, num[1]*inv);
    ov.u[1] = cvtpk(num[2]*inv, num[3]*inv);
    ov.u[2] = cvtpk(num[4]*inv, num[5]*inv);
    ov.u[3] = cvtpk(num[6]*inv, num[7]*inv);
    *(short8*)&out[((size_t)(b*1024 + r0 + row))*1152 + h*64 + ds8] = ov.v;
  }
}

extern "C" void kernel_launch(void* const* d_in, const int* in_sizes, int n_in,
                              void* d_out, int out_size, void* d_ws, size_t ws_size,
                              hipStream_t stream)
{
  const float* x    = (const float*)d_in[0];
  const float* t    = (const float*)d_in[1];
  const float* ln1g = (const float*)d_in[2];
  const float* ln1b = (const float*)d_in[3];
  const float* qkvw = (const float*)d_in[4];
  const float* qkvb = (const float*)d_in[5];
  const float* timew= (const float*)d_in[6];
  const float* timeb= (const float*)d_in[7];
  const float* outw = (const float*)d_in[8];
  const float* outbv= (const float*)d_in[9];
  const float* Er   = (const float*)d_in[10];
  const float* ln2g = (const float*)d_in[11];
  const float* ln2b = (const float*)d_in[12];
  const float* ff1w = (const float*)d_in[13];
  const float* ff1b = (const float*)d_in[14];
  const float* ff2w = (const float*)d_in[15];
  const float* ff2b = (const float*)d_in[16];
  float* o = (float*)d_out;

  char* ws = (char*)d_ws;
  ushort* qkvw_t = (ushort*)(ws);              // [3072][1152]
  ushort* outw_t = (ushort*)(ws + 7077888);    // [1024][1152]
  ushort* ff1w_t = (ushort*)(ws + 9437184);    // [4096][1152]
  ushort* ff2w_t = (ushort*)(ws + 18874368);   // [1024][4224]
  ushort* er_b   = (ushort*)(ws + 27525120);   // [1024][64]
  float*  tq     = (float*) (ws + 27656192);   // [4][3072]
  ushort* bufA   = (ushort*)(ws + 27705344);   // [4096][1152]
  ushort* vt     = (ushort*)(ws + 37142528);   // [4096][1152]
  ushort* bufB   = (ushort*)(ws + 46579712);   // [4096][4224] (qkv at stride 3200 / ff1o at 4224)

  wt_cvt<<<dim3(48,16),256,0,stream>>>(qkvw, qkvw_t, 1024, 3072, 1152);
  wt_cvt<<<dim3(16,16),256,0,stream>>>(outw, outw_t, 1024, 1024, 1152);
  wt_cvt<<<dim3(64,16),256,0,stream>>>(ff1w, ff1w_t, 1024, 4096, 1152);
  wt_cvt<<<dim3(16,64),256,0,stream>>>(ff2w, ff2w_t, 4096, 1024, 4224);
  cvt_f2b<<<256,256,0,stream>>>(Er, er_b, 65536);

  ln_rows<<<4096,256,0,stream>>>(x, ln1g, ln1b, bufA, 1152);
  tq_gemm2<<<48,256,0,stream>>>(t, timew, timeb, tq);
  gemm4<0,128><<<768,256,0,stream>>>(bufA, qkvw_t, qkvb, tq, bufB, nullptr,
                                     1024, 1152, 1152, 3200, 3072, 24);
  vt_k<<<dim3(16,64),256,0,stream>>>(bufB, vt);
  attn8<<<2048,256,0,stream>>>(bufB, er_b, vt, bufA);
  gemm4<1,64><<<512,256,0,stream>>>(bufA, outw_t, outbv, x, nullptr, o,
                                    1024, 1152, 1152, 1024, 1024, 16);
  ln_rows<<<4096,256,0,stream>>>(o, ln2g, ln2b, bufA, 1152);
  gemm4<2,128><<<1024,256,0,stream>>>(bufA, ff1w_t, ff1b, nullptr, bufB, nullptr,
                                      1024, 1152, 1152, 4224, 0, 32);
  gemm4<1,64><<<512,256,0,stream>>>(bufB, ff2w_t, ff2b, o, nullptr, o,
                                    4096, 4224, 4224, 1024, 1024, 16);
}

// Round 10
// 395.507 us; speedup vs baseline: 1.0986x; 1.0986x over previous
//
#include <hip/hip_runtime.h>
#include <hip/hip_bf16.h>

typedef __attribute__((ext_vector_type(8))) short short8;
typedef __attribute__((ext_vector_type(4))) float f32x4;
typedef __attribute__((ext_vector_type(16))) float f32x16;

#define DEV __device__ __forceinline__

DEV float bf2f(ushort u){ union { float f; unsigned int i; } x; x.i = ((unsigned int)u)<<16; return x.f; }
DEV ushort f2bf(float f){ union { float fl; unsigned int i; } x; x.fl = f; unsigned int r = x.i + 0x7fffu + ((x.i>>16)&1u); return (ushort)(r>>16); }

DEV void gl2lds16(const ushort* g, ushort* l){
  __builtin_amdgcn_global_load_lds((const __attribute__((address_space(1))) void*)g,
                                   (__attribute__((address_space(3))) void*)l, 16, 0, 0);
}
DEV f32x16 mfma32(short8 a, short8 b, f32x16 c){
  return __builtin_amdgcn_mfma_f32_32x32x16_bf16(a, b, c, 0, 0, 0);
}
DEV uint cvtpk(float lo, float hi){
  uint r; asm("v_cvt_pk_bf16_f32 %0, %1, %2" : "=v"(r) : "v"(lo), "v"(hi));
  return r;
}
DEV uint q8(float v){
  float c = fminf(fmaxf(v, -127.f), 127.f);
  return ((uint)(int)rintf(c)) & 255u;
}

// ---------------- fp32 -> bf16 convert (Er only) ----------------
__global__ void cvt_f2b(const float* __restrict__ in, ushort* __restrict__ out, int n){
  int i = blockIdx.x*blockDim.x + threadIdx.x;
  int stride = gridDim.x*blockDim.x;
  for (; i < n; i += stride) out[i] = f2bf(in[i]);
}

// ---------------- fp32 [K][N] -> bf16 [N][K+pad] tiled transpose ----------------
__global__ __launch_bounds__(256) void wt_cvt(const float* __restrict__ in, ushort* __restrict__ out,
                                              int K, int N, int ldk){
  const int n0 = blockIdx.x*64, k0 = blockIdx.y*64;
  __shared__ float T[64][65];
  const int tid = threadIdx.x;
  const int r = tid>>4, c = (tid&15)*4;
  #pragma unroll
  for (int p=0;p<4;p++){
    float4 v = *(const float4*)&in[(size_t)(k0 + p*16 + r)*N + n0 + c];
    T[p*16+r][c+0]=v.x; T[p*16+r][c+1]=v.y; T[p*16+r][c+2]=v.z; T[p*16+r][c+3]=v.w;
  }
  __syncthreads();
  #pragma unroll
  for (int p=0;p<4;p++){
    int n = p*16 + r;
    ushort u0 = f2bf(T[c+0][n]), u1 = f2bf(T[c+1][n]), u2 = f2bf(T[c+2][n]), u3 = f2bf(T[c+3][n]);
    ushort4 u = make_ushort4(u0,u1,u2,u3);
    *(ushort4*)&out[(size_t)(n0+n)*ldk + k0 + c] = u;
  }
}

// ---------------- V transpose: qkv V-part [n][hd] -> Vt [(bh*64+hd)][n] ----------------
__global__ __launch_bounds__(256) void vt_k(const ushort* __restrict__ qkv, ushort* __restrict__ vt){
  const int bh = blockIdx.y; const int b = bh>>4, h = bh&15;
  const int n0 = blockIdx.x*64;
  __shared__ ushort T[64][66];
  const int tid = threadIdx.x;
  const int r = tid>>3, c8 = (tid&7)*8;
  #pragma unroll
  for (int p=0;p<2;p++){
    int row = p*32 + r;
    short8 v = *(const short8*)&qkv[(size_t)(b*1024 + n0 + row)*3200 + 2048 + h*64 + c8];
    #pragma unroll
    for (int i=0;i<8;i++) T[row][c8+i] = ((ushort*)&v)[i];
  }
  __syncthreads();
  #pragma unroll
  for (int p=0;p<2;p++){
    int d = p*32 + r;
    union { ushort u[8]; short8 v; } o;
    #pragma unroll
    for (int i=0;i<8;i++) o.u[i] = T[c8+i][d];
    *(short8*)&vt[(size_t)(bh*64 + d)*1152 + n0 + c8] = o.v;
  }
}

// ---------------- LayerNorm over C=1024 ----------------
__global__ __launch_bounds__(256) void ln_rows(const float* __restrict__ in,
                                               const float* __restrict__ g,
                                               const float* __restrict__ bta,
                                               ushort* __restrict__ out, int ldo){
  int row = blockIdx.x; int tid = threadIdx.x;
  const float* x = in + (size_t)row*1024;
  float v[4]; float s = 0.f;
  #pragma unroll
  for (int i=0;i<4;i++){ v[i] = x[tid + 256*i]; s += v[i]; }
  __shared__ float rbuf[256];
  rbuf[tid] = s; __syncthreads();
  for (int off=128; off>0; off>>=1){ if (tid<off) rbuf[tid]+=rbuf[tid+off]; __syncthreads(); }
  float mean = rbuf[0] * (1.f/1024.f);
  __syncthreads();
  float s2 = 0.f;
  #pragma unroll
  for (int i=0;i<4;i++){ float d=v[i]-mean; s2 += d*d; }
  rbuf[tid] = s2; __syncthreads();
  for (int off=128; off>0; off>>=1){ if (tid<off) rbuf[tid]+=rbuf[tid+off]; __syncthreads(); }
  float var = rbuf[0] * (1.f/1024.f);
  float rstd = rsqrtf(var + 1e-5f);
  #pragma unroll
  for (int i=0;i<4;i++){ int c = tid+256*i; out[(size_t)row*ldo+c] = f2bf((v[i]-mean)*rstd*g[c]+bta[c]); }
}

// ---------------- time-embedding GEMM ----------------
__global__ __launch_bounds__(256) void tq_gemm2(const float* __restrict__ t, const float* __restrict__ tw,
                                                const float* __restrict__ tb, float* __restrict__ tq){
  const int tid = threadIdx.x;
  const int j = blockIdx.x*64 + (tid & 63);
  const int sl = tid >> 6;
  float acc[4] = {0.f,0.f,0.f,0.f};
  for (int k = sl*64; k < sl*64+64; ++k){
    float wv = tw[(size_t)k*3072 + j];
    #pragma unroll
    for (int b=0;b<4;b++) acc[b] = fmaf(t[b*256+k], wv, acc[b]);
  }
  __shared__ float red[4][4][64];
  #pragma unroll
  for (int b=0;b<4;b++) red[sl][b][tid&63] = acc[b];
  __syncthreads();
  if (sl == 0){
    #pragma unroll
    for (int b=0;b<4;b++)
      tq[b*3072 + j] = red[0][b][tid&63] + red[1][b][tid&63] + red[2][b][tid&63] + red[3][b][tid&63] + tb[j];
  }
}

// ---------------- gemm4: 128xTN tile, BK=32, double-buffered LDS 2-phase pipeline ----------------
template<int EPI, int TN>
__global__ __launch_bounds__(256) void gemm4(
    const ushort* __restrict__ A, const ushort* __restrict__ Bt,
    const float* __restrict__ bias, const float* __restrict__ extra,
    ushort* __restrict__ outb, float* __restrict__ outf,
    int K, int lda, int ldb, int ldo, int lde, int nbx)
{
  constexpr int NJ = TN/32;
  __shared__ __align__(16) ushort Al[2][128*32];
  __shared__ __align__(16) ushort Bl[2][TN*32];
  const int nwg = gridDim.x, cpx = nwg >> 3;
  const int bid = blockIdx.x;
  const int swz = (bid & 7)*cpx + (bid >> 3);
  const int m0 = (swz / nbx)*128, n0 = (swz % nbx)*TN;
  const int tid = threadIdx.x, lane = tid & 63, wid = tid >> 6;
  const int wm = (wid&1)*64, wn = (wid>>1)*(TN/2);
  const int l15 = lane&15, l4 = lane>>4;
  f32x4 acc[4][NJ];
  #pragma unroll
  for (int i=0;i<4;i++)
    #pragma unroll
    for (int jx=0;jx<NJ;jx++){ acc[i][jx][0]=0.f; acc[i][jx][1]=0.f; acc[i][jx][2]=0.f; acc[i][jx][3]=0.f; }
  const ushort* a0p = A + (size_t)(m0 + (tid>>2))*lda + (tid&3)*8;
  const ushort* a1p = A + (size_t)(m0 + 64 + (tid>>2))*lda + (tid&3)*8;
  const ushort* b0p = Bt + (size_t)(n0 + (tid>>2))*ldb + (tid&3)*8;
  const ushort* b1p = nullptr;
  if constexpr (TN==128) b1p = Bt + (size_t)(n0 + 64 + (tid>>2))*ldb + (tid&3)*8;
  const int lsl = tid*8, lsh = (tid+256)*8;

  gl2lds16(a0p, &Al[0][lsl]);
  gl2lds16(a1p, &Al[0][lsh]);
  gl2lds16(b0p, &Bl[0][lsl]);
  if constexpr (TN==128) gl2lds16(b1p, &Bl[0][lsh]);
  __syncthreads();

  const int nk = K >> 5;
  for (int it=0; it<nk; ++it){
    const int cur = it & 1;
    ushort* Ac = Al[cur];  ushort* Bc = Bl[cur];
    if (it+1 < nk){
      const int k1 = (it+1) << 5;
      gl2lds16(a0p + k1, &Al[cur^1][lsl]);
      gl2lds16(a1p + k1, &Al[cur^1][lsh]);
      gl2lds16(b0p + k1, &Bl[cur^1][lsl]);
      if constexpr (TN==128) gl2lds16(b1p + k1, &Bl[cur^1][lsh]);
    }
    short8 af[4], bfr[NJ];
    #pragma unroll
    for (int mi=0;mi<4;mi++) af[mi]  = *(const short8*)&Ac[(wm + mi*16 + l15)*32 + l4*8];
    #pragma unroll
    for (int nj=0;nj<NJ;nj++) bfr[nj] = *(const short8*)&Bc[(wn + nj*16 + l15)*32 + l4*8];
    #pragma unroll
    for (int mi=0;mi<4;mi++)
      #pragma unroll
      for (int nj=0;nj<NJ;nj++)
        acc[mi][nj] = __builtin_amdgcn_mfma_f32_16x16x32_bf16(af[mi], bfr[nj], acc[mi][nj], 0,0,0);
    __syncthreads();
  }
  #pragma unroll
  for (int mi=0;mi<4;mi++)
    #pragma unroll
    for (int nj=0;nj<NJ;nj++)
      #pragma unroll
      for (int j=0;j<4;j++){
        int row = m0 + wm + mi*16 + l4*4 + j;
        int col = n0 + wn + nj*16 + l15;
        float v = acc[mi][nj][j] + bias[col];
        if constexpr (EPI==0){ v += extra[(size_t)(row>>10)*lde + col]; outb[(size_t)row*ldo+col] = f2bf(v); }
        else if constexpr (EPI==1){ v += extra[(size_t)row*lde + col]; outf[(size_t)row*ldo+col] = v; }
        else { v = 0.5f*v*(1.f+erff(v*0.70710678118f)); outb[(size_t)row*ldo+col] = f2bf(v); }
      }
}

// ---------------- attn8b: int8-bias LDS rel-skew + fixed-base (M=0) 32x32 flash ----------------
// Same as R9 attn8 but with plain __launch_bounds__(256): R9's (256,4) forced a 64-VGPR budget
// and spilled the whole inner-loop state to scratch (WRITE_SIZE 8->100 MB). LDS 34.8 KB still
// allows 4 WG/CU at ~96-128 VGPR.
__global__ __launch_bounds__(256) void attn8b(
    const ushort* __restrict__ qkv, const ushort* __restrict__ Er,
    const ushort* __restrict__ Vt, ushort* __restrict__ out)
{
  const int bid0 = blockIdx.x;
  const int swz = (bid0 & 7)*256 + (bid0 >> 3);
  const int bh = swz >> 5, b = bh >> 4, h = bh & 15;
  const int rt = swz & 31;
  const int r0 = rt*32;
  const int tid = threadIdx.x, w = tid >> 6, lane = tid & 63;
  const int l31 = lane & 31, hi = lane >> 5;

  __shared__ __align__(16) signed char RRF8[34704];   // 33x1036 int8 bias (34188) + lsum[4][32] @34192
  ushort* Obuf = (ushort*)RRF8;                       // aliased after phase-2: [4][32][68]
  float*  ml   = (float*)(RRF8 + 34192);              // [4][32] lsum

  const ushort* Qp = qkv + (size_t)b*1024*3200 + h*64;
  const ushort* Kp = Qp + 1024;
  const ushort* Vp = Vt + (size_t)bh*64*1152;

  const int r = r0 + l31;
  short8 qf0 = *(const short8*)(Qp + (size_t)r*3200 +      hi*8);
  short8 qf1 = *(const short8*)(Qp + (size_t)r*3200 + 16 + hi*8);
  short8 qf2 = *(const short8*)(Qp + (size_t)r*3200 + 32 + hi*8);
  short8 qf3 = *(const short8*)(Qp + (size_t)r*3200 + 48 + hi*8);

  if (tid < 32) RRF8[tid*1036 + 1035] = 0;            // diagonal-zero slots

  // Phase 1: RR rows r0..r0+31 (wave w covers e-quarter), int8 encode (x 64*log2e)
  const float ESC = 92.332481f;                       // 64 * log2(e)
  for (int t=0; t<8; ++t){
    const int e0 = w*256 + t*32;
    const ushort* ep = Er + (size_t)(e0 + l31)*64 + hi*8;
    short8 ea0 = *(const short8*)(ep);
    short8 ea1 = *(const short8*)(ep + 16);
    short8 ea2 = *(const short8*)(ep + 32);
    short8 ea3 = *(const short8*)(ep + 48);
    f32x16 acc = {};
    acc = mfma32(ea0, qf0, acc);
    acc = mfma32(ea1, qf1, acc);
    acc = mfma32(ea2, qf2, acc);
    acc = mfma32(ea3, qf3, acc);
    #pragma unroll
    for (int q=0;q<4;q++){
      int e = e0 + 8*q + 4*hi;
      uint u = q8(acc[4*q+0]*ESC) | (q8(acc[4*q+1]*ESC)<<8)
             | (q8(acc[4*q+2]*ESC)<<16) | (q8(acc[4*q+3]*ESC)<<24);
      *(uint*)(RRF8 + l31*1036 + e) = u;
    }
  }
  // extra row r0+32 (upper-diagonal source for q-row r0+31): VALU dot, 4 e per thread
  {
    const int q32r = min(r0 + 32, 1023);              // r0=992's row-32 slice is never read
    const ushort* q32 = Qp + (size_t)q32r*3200;
    const int e4 = tid*4;
    float a[4] = {0.f,0.f,0.f,0.f};
    #pragma unroll
    for (int c8=0;c8<8;c8++){
      short8 qv = *(const short8*)(q32 + c8*8);
      float qx[8];
      #pragma unroll
      for (int i=0;i<8;i++) qx[i] = bf2f(((ushort*)&qv)[i]);
      #pragma unroll
      for (int e=0;e<4;e++){
        short8 ev = *(const short8*)(Er + (size_t)(e4+e)*64 + c8*8);
        #pragma unroll
        for (int i=0;i<8;i++) a[e] = fmaf(qx[i], bf2f(((ushort*)&ev)[i]), a[e]);
      }
    }
    uint u = q8(a[0]*ESC) | (q8(a[1]*ESC)<<8) | (q8(a[2]*ESC)<<16) | (q8(a[3]*ESC)<<24);
    *(uint*)(RRF8 + 33152 + e4) = u;
  }
  __syncthreads();

  // Phase 2: flash over this wave's kv quarter (8 tiles of 32), fixed-base softmax
  const int rbase = l31*1036;
  const int kvbase = w*256;
  f32x16 O0 = {}, O1 = {};
  float lsum = 0.f;

  short8 kA0 = *(const short8*)(Kp + (size_t)(kvbase + l31)*3200 +      hi*8);
  short8 kA1 = *(const short8*)(Kp + (size_t)(kvbase + l31)*3200 + 16 + hi*8);
  short8 kA2 = *(const short8*)(Kp + (size_t)(kvbase + l31)*3200 + 32 + hi*8);
  short8 kA3 = *(const short8*)(Kp + (size_t)(kvbase + l31)*3200 + 48 + hi*8);
  short8 kB0, kB1, kB2, kB3;

  auto step = [&](short8& ka0, short8& ka1, short8& ka2, short8& ka3,
                  short8& kn0, short8& kn1, short8& kn2, short8& kn3, int t){
    const int c0 = kvbase + t*32;
    if (t < 7){
      const ushort* kp = Kp + (size_t)(c0 + 32 + l31)*3200 + hi*8;
      kn0 = *(const short8*)(kp);
      kn1 = *(const short8*)(kp + 16);
      kn2 = *(const short8*)(kp + 32);
      kn3 = *(const short8*)(kp + 48);
    }
    // bias reads (int8, hoisted; hide under QK MFMAs)
    signed char bs[16];
    #pragma unroll
    for (int q=0;q<4;q++)
      #pragma unroll
      for (int j=0;j<4;j++){
        int c = c0 + 8*q + 4*hi + j;
        int d = c - r;
        int off = (d<=0) ? (1023+d) : (1034+d);
        bs[4*q+j] = RRF8[rbase + off];
      }
    short8 v00 = *(const short8*)(Vp + (size_t)l31*1152      + c0 +      hi*8);
    short8 v01 = *(const short8*)(Vp + (size_t)l31*1152      + c0 + 16 + hi*8);
    short8 v10 = *(const short8*)(Vp + (size_t)(32+l31)*1152 + c0 +      hi*8);
    short8 v11 = *(const short8*)(Vp + (size_t)(32+l31)*1152 + c0 + 16 + hi*8);
    f32x16 S = {};
    __builtin_amdgcn_s_setprio(1);
    S = mfma32(ka0, qf0, S);
    S = mfma32(ka1, qf1, S);
    S = mfma32(ka2, qf2, S);
    S = mfma32(ka3, qf3, S);
    __builtin_amdgcn_s_setprio(0);
    float p[16];
    float s0=0.f, s1=0.f, s2=0.f, s3=0.f;
    #pragma unroll
    for (int i=0;i<16;i++){
      p[i] = __builtin_amdgcn_exp2f(fmaf(S[i], 0.18033688f, (float)bs[i]*0.015625f));
      if ((i&3)==0) s0 += p[i]; else if ((i&3)==1) s1 += p[i];
      else if ((i&3)==2) s2 += p[i]; else s3 += p[i];
    }
    lsum += (s0+s1)+(s2+s3);
    uint W00=cvtpk(p[0],p[1]),   W01=cvtpk(p[2],p[3]);
    uint W10=cvtpk(p[4],p[5]),   W11=cvtpk(p[6],p[7]);
    uint W20=cvtpk(p[8],p[9]),   W21=cvtpk(p[10],p[11]);
    uint W30=cvtpk(p[12],p[13]), W31=cvtpk(p[14],p[15]);
    uint x00 = (uint)__shfl_xor((int)(hi? W00 : W10), 32, 64);
    uint x01 = (uint)__shfl_xor((int)(hi? W01 : W11), 32, 64);
    uint x10 = (uint)__shfl_xor((int)(hi? W20 : W30), 32, 64);
    uint x11 = (uint)__shfl_xor((int)(hi? W21 : W31), 32, 64);
    union { uint u[4]; short8 v; } pf0, pf1;
    pf0.u[0] = hi ? x00 : W00;  pf0.u[1] = hi ? x01 : W01;
    pf0.u[2] = hi ? W10 : x00;  pf0.u[3] = hi ? W11 : x01;
    pf1.u[0] = hi ? x10 : W20;  pf1.u[1] = hi ? x11 : W21;
    pf1.u[2] = hi ? W30 : x10;  pf1.u[3] = hi ? W31 : x11;
    __builtin_amdgcn_s_setprio(1);
    O0 = mfma32(v00, pf0.v, O0);
    O0 = mfma32(v01, pf1.v, O0);
    O1 = mfma32(v10, pf0.v, O1);
    O1 = mfma32(v11, pf1.v, O1);
    __builtin_amdgcn_s_setprio(0);
  };
  for (int t=0;t<8;t+=2){
    step(kA0,kA1,kA2,kA3, kB0,kB1,kB2,kB3, t);
    step(kB0,kB1,kB2,kB3, kA0,kA1,kA2,kA3, t+1);
  }
  lsum = lsum + __shfl_xor(lsum, 32, 64);

  __syncthreads();   // all RRF8 bias reads done; safe to alias Obuf
  #pragma unroll
  for (int q=0;q<4;q++){
    int d = 8*q + 4*hi;
    uint2 w0, w1;
    w0.x = cvtpk(O0[4*q+0], O0[4*q+1]); w0.y = cvtpk(O0[4*q+2], O0[4*q+3]);
    w1.x = cvtpk(O1[4*q+0], O1[4*q+1]); w1.y = cvtpk(O1[4*q+2], O1[4*q+3]);
    *(uint2*)&Obuf[(w*32 + l31)*68 + d] = w0;
    *(uint2*)&Obuf[(w*32 + l31)*68 + 32 + d] = w1;
  }
  if (hi == 0) ml[w*32 + l31] = lsum;
  __syncthreads();
  // 4-way merge: plain sums (all waves share base M=0)
  {
    const int row = tid >> 3, ds8 = (tid & 7)*8;
    float den = ml[row] + ml[32+row] + ml[64+row] + ml[96+row];
    float inv = 1.f/den;
    float num[8] = {0.f,0.f,0.f,0.f,0.f,0.f,0.f,0.f};
    #pragma unroll
    for (int w2=0;w2<4;w2++){
      uint2 o0 = *(const uint2*)&Obuf[(w2*32 + row)*68 + ds8];
      uint2 o1 = *(const uint2*)&Obuf[(w2*32 + row)*68 + ds8 + 4];
      const ushort* ou0 = (const ushort*)&o0;
      const ushort* ou1 = (const ushort*)&o1;
      #pragma unroll
      for (int i=0;i<4;i++){ num[i] += bf2f(ou0[i]); num[4+i] += bf2f(ou1[i]); }
    }
    union { uint u[4]; short8 v; } ov;
    ov.u[0] = cvtpk(num[0]*inv, num[1]*inv);
    ov.u[1] = cvtpk(num[2]*inv, num[3]*inv);
    ov.u[2] = cvtpk(num[4]*inv, num[5]*inv);
    ov.u[3] = cvtpk(num[6]*inv, num[7]*inv);
    *(short8*)&out[((size_t)(b*1024 + r0 + row))*1152 + h*64 + ds8] = ov.v;
  }
}

extern "C" void kernel_launch(void* const* d_in, const int* in_sizes, int n_in,
                              void* d_out, int out_size, void* d_ws, size_t ws_size,
                              hipStream_t stream)
{
  const float* x    = (const float*)d_in[0];
  const float* t    = (const float*)d_in[1];
  const float* ln1g = (const float*)d_in[2];
  const float* ln1b = (const float*)d_in[3];
  const float* qkvw = (const float*)d_in[4];
  const float* qkvb = (const float*)d_in[5];
  const float* timew= (const float*)d_in[6];
  const float* timeb= (const float*)d_in[7];
  const float* outw = (const float*)d_in[8];
  const float* outbv= (const float*)d_in[9];
  const float* Er   = (const float*)d_in[10];
  const float* ln2g = (const float*)d_in[11];
  const float* ln2b = (const float*)d_in[12];
  const float* ff1w = (const float*)d_in[13];
  const float* ff1b = (const float*)d_in[14];
  const float* ff2w = (const float*)d_in[15];
  const float* ff2b = (const float*)d_in[16];
  float* o = (float*)d_out;

  char* ws = (char*)d_ws;
  ushort* qkvw_t = (ushort*)(ws);              // [3072][1152]
  ushort* outw_t = (ushort*)(ws + 7077888);    // [1024][1152]
  ushort* ff1w_t = (ushort*)(ws + 9437184);    // [4096][1152]
  ushort* ff2w_t = (ushort*)(ws + 18874368);   // [1024][4224]
  ushort* er_b   = (ushort*)(ws + 27525120);   // [1024][64]
  float*  tq     = (float*) (ws + 27656192);   // [4][3072]
  ushort* bufA   = (ushort*)(ws + 27705344);   // [4096][1152]
  ushort* vt     = (ushort*)(ws + 37142528);   // [4096][1152]
  ushort* bufB   = (ushort*)(ws + 46579712);   // [4096][4224] (qkv at stride 3200 / ff1o at 4224)

  wt_cvt<<<dim3(48,16),256,0,stream>>>(qkvw, qkvw_t, 1024, 3072, 1152);
  wt_cvt<<<dim3(16,16),256,0,stream>>>(outw, outw_t, 1024, 1024, 1152);
  wt_cvt<<<dim3(64,16),256,0,stream>>>(ff1w, ff1w_t, 1024, 4096, 1152);
  wt_cvt<<<dim3(16,64),256,0,stream>>>(ff2w, ff2w_t, 4096, 1024, 4224);
  cvt_f2b<<<256,256,0,stream>>>(Er, er_b, 65536);

  ln_rows<<<4096,256,0,stream>>>(x, ln1g, ln1b, bufA, 1152);
  tq_gemm2<<<48,256,0,stream>>>(t, timew, timeb, tq);
  gemm4<0,128><<<768,256,0,stream>>>(bufA, qkvw_t, qkvb, tq, bufB, nullptr,
                                     1024, 1152, 1152, 3200, 3072, 24);
  vt_k<<<dim3(16,64),256,0,stream>>>(bufB, vt);
  attn8b<<<2048,256,0,stream>>>(bufB, er_b, vt, bufA);
  gemm4<1,64><<<512,256,0,stream>>>(bufA, outw_t, outbv, x, nullptr, o,
                                    1024, 1152, 1152, 1024, 1024, 16);
  ln_rows<<<4096,256,0,stream>>>(o, ln2g, ln2b, bufA, 1152);
  gemm4<2,128><<<1024,256,0,stream>>>(bufA, ff1w_t, ff1b, nullptr, bufB, nullptr,
                                      1024, 1152, 1152, 4224, 0, 32);
  gemm4<1,64><<<512,256,0,stream>>>(bufB, ff2w_t, ff2b, o, nullptr, o,
                                    4096, 4224, 4224, 1024, 1024, 16);
}